// Round 8
// baseline (73.406 us; speedup 1.0000x reference)
//
#include <hip/hip_runtime.h>
#include <hip/hip_bf16.h>
#include <stdint.h>

typedef float  f32x4  __attribute__((ext_vector_type(4)));
typedef float  f32x16 __attribute__((ext_vector_type(16)));
typedef _Float16 half8 __attribute__((ext_vector_type(8)));
typedef unsigned int uint32;

#define N1 256
#define N2T 32768
#define BQ 512
#define KT 32
#define TILE_B 16384

// flash LDS: rowA [2][16384] @0 (32 pat rows x 512B, granule g at g^(r&7))
//            memT [2][16384] @32768 (256 d rows x 64B, granule g at g^((d>>1)&3))
#define RA_OFF 0
#define MT_OFF 32768
#define LDS_BYTES 65536

union H4 { _Float16 h[4]; unsigned short s[4]; uint2 u2; };

#define GLD_LDS(gp, lp) __builtin_amdgcn_global_load_lds( \
    (const __attribute__((address_space(1))) void*)(gp), \
    (__attribute__((address_space(3))) void*)(lp), 16, 0, 0)

// ---- prep: Mem f32 -> MemA / MemT (f16, pre-swizzled) + m2 (exact f32). ----
__global__ __launch_bounds__(256) void mhn_prep_k(
    const float* __restrict__ Mem, _Float16* __restrict__ MemA,
    _Float16* __restrict__ MemT, float* __restrict__ m2g)
{
  const int t   = blockIdx.x;
  const int tid = threadIdx.x;
  const int a    = tid >> 4;
  const int dblk = tid & 15;
  const int r0i  = 32*t + 2*a;

  const float* p0 = Mem + (size_t)r0i*N1 + dblk*16;
  const float* p1 = p0 + N1;
  float4 x0[4], x1[4];
  #pragma unroll
  for (int i=0;i<4;i++){ x0[i] = *(const float4*)(p0+4*i); x1[i] = *(const float4*)(p1+4*i); }

  float s0=0.f, s1=0.f;
  H4 h0[4], h1[4];
  #pragma unroll
  for (int i=0;i<4;i++){
    s0 += x0[i].x*x0[i].x + x0[i].y*x0[i].y + x0[i].z*x0[i].z + x0[i].w*x0[i].w;
    s1 += x1[i].x*x1[i].x + x1[i].y*x1[i].y + x1[i].z*x1[i].z + x1[i].w*x1[i].w;
    h0[i].h[0]=(_Float16)x0[i].x; h0[i].h[1]=(_Float16)x0[i].y; h0[i].h[2]=(_Float16)x0[i].z; h0[i].h[3]=(_Float16)x0[i].w;
    h1[i].h[0]=(_Float16)x1[i].x; h1[i].h[1]=(_Float16)x1[i].y; h1[i].h[2]=(_Float16)x1[i].z; h1[i].h[3]=(_Float16)x1[i].w;
  }

  char* bA = (char*)MemA + (size_t)t*TILE_B;
  {
    const int e0 = (2*a)&7, e1 = (2*a+1)&7;
    uint4 wv;
    wv.x=h0[0].u2.x; wv.y=h0[0].u2.y; wv.z=h0[1].u2.x; wv.w=h0[1].u2.y;
    *(uint4*)(bA + (2*a)*512   + (((2*dblk  )^e0)<<4)) = wv;
    wv.x=h0[2].u2.x; wv.y=h0[2].u2.y; wv.z=h0[3].u2.x; wv.w=h0[3].u2.y;
    *(uint4*)(bA + (2*a)*512   + (((2*dblk+1)^e0)<<4)) = wv;
    wv.x=h1[0].u2.x; wv.y=h1[0].u2.y; wv.z=h1[1].u2.x; wv.w=h1[1].u2.y;
    *(uint4*)(bA + (2*a+1)*512 + (((2*dblk  )^e1)<<4)) = wv;
    wv.x=h1[2].u2.x; wv.y=h1[2].u2.y; wv.z=h1[3].u2.x; wv.w=h1[3].u2.y;
    *(uint4*)(bA + (2*a+1)*512 + (((2*dblk+1)^e1)<<4)) = wv;
  }

  char* bT = (char*)MemT + (size_t)t*TILE_B;
  #pragma unroll
  for (int i=0;i<4;i++){
    #pragma unroll
    for (int j=0;j<4;j++){
      const int d = dblk*16 + 4*i + j;
      const uint32 pk = (uint32)h0[i].s[j] | ((uint32)h1[i].s[j] << 16);
      *(uint32*)(bT + d*64 + ((((a>>2) ^ ((d>>1)&3)))<<4) + ((a&3)<<2)) = pk;
    }
  }

  s0 += __shfl_xor(s0,1); s0 += __shfl_xor(s0,2); s0 += __shfl_xor(s0,4); s0 += __shfl_xor(s0,8);
  s1 += __shfl_xor(s1,1); s1 += __shfl_xor(s1,2); s1 += __shfl_xor(s1,4); s1 += __shfl_xor(s1,8);
  if (dblk == 0){ m2g[r0i] = -0.5f*s0; m2g[r0i+1] = -0.5f*s1; }
}

// ---- flash: 32x32x16 MFMA; wave owns 32 q; O computed transposed (rows=d, cols=q) ----
__global__ __launch_bounds__(256, 2) void mhn_flash_k(
    const _Float16* __restrict__ MemA, const _Float16* __restrict__ MemT,
    const float* __restrict__ m2g, const float* __restrict__ v,
    __hip_bfloat16* __restrict__ Opart, float* __restrict__ mpart,
    float* __restrict__ lpart, int CK, int nt)
{
  __shared__ __align__(16) char lds[LDS_BYTES];

  const int tid = threadIdx.x;
  const int w   = tid >> 6;
  const int l   = tid & 63;
  const int row = l & 31;
  const int hi  = l >> 5;

  const int nwg = gridDim.x;
  const int bid = blockIdx.x;
  const int s_  = (bid & 7) * (nwg >> 3) + (bid >> 3);
  const int c   = s_ >> 2;
  const int qb  = s_ & 3;

  const uint32 dmaL = (uint32)(w*4096 + l*16);
  const char* gA = (const char*)MemA + (size_t)(c*(CK>>5))*TILE_B + dmaL;
  const char* gT = (const char*)MemT + (size_t)(c*(CK>>5))*TILE_B + dmaL;
  char* const dA0 = lds + RA_OFF + dmaL;
  char* const dT0 = lds + MT_OFF + dmaL;

  #pragma unroll
  for (int i=0;i<4;i++){
    GLD_LDS(gA + i*1024, dA0 + i*1024);
    GLD_LDS(gT + i*1024, dT0 + i*1024);
  }
  gA += TILE_B; gT += TILE_B;

  half8 v8[16];
  const int q0 = qb*128 + w*32;
  {
    const float* vp = v + (size_t)(q0 + row)*N1 + 8*hi;
    #pragma unroll
    for (int s=0;s<16;s++){
      const float4 a = *(const float4*)(vp + 16*s);
      const float4 b = *(const float4*)(vp + 16*s + 4);
      half8 hv;
      hv[0]=(_Float16)a.x; hv[1]=(_Float16)a.y; hv[2]=(_Float16)a.z; hv[3]=(_Float16)a.w;
      hv[4]=(_Float16)b.x; hv[5]=(_Float16)b.y; hv[6]=(_Float16)b.z; hv[7]=(_Float16)b.w;
      v8[s]=hv;
    }
  }

  float mrun = -INFINITY, lrun = 0.f;
  f32x16 oacc[8];
  #pragma unroll
  for (int b=0;b<8;b++) oacc[b] = (f32x16)(0.f);

  const int e7 = row & 7;
  const uint32 qkB = (uint32)(row*512 + ((hi ^ (e7 & 1)) << 4) + ((e7 >> 1) << 5));
  const int sd = (row >> 1) & 3;
  const uint32 pvB = (uint32)(row*64 + ((hi ^ (sd & 1)) << 4) + ((sd >> 1) << 5));

  const float* m2p = m2g + c*CK + 4*hi;

  __syncthreads();

  for (int tt=0; tt<nt; ++tt){
    const uint32 bufO = (uint32)(tt & 1)*TILE_B;
    const bool pf = (tt+1 < nt);
    if (pf){
      const char* sA = gA; const char* sT = gT;
      char* dA = dA0 + (bufO ^ TILE_B);
      char* dT = dT0 + (bufO ^ TILE_B);
      #pragma unroll
      for (int i=0;i<4;i++){
        GLD_LDS(sA + i*1024, dA + i*1024);
        GLD_LDS(sT + i*1024, dT + i*1024);
      }
      gA += TILE_B; gT += TILE_B;
    }

    f32x4 m2v[4];
    #pragma unroll
    for (int b=0;b<4;b++) m2v[b] = *(const f32x4*)(m2p + 8*b);

    // ---- QK^T with explicit 4-deep LDS read-ahead ----
    const char* ra = lds + RA_OFF + bufO;
    half8 aq[4];
    #pragma unroll
    for (int i=0;i<4;i++) aq[i] = *(const half8*)(ra + (qkB ^ (uint32)(i<<5)));
    f32x16 S = (f32x16)(0.f);
    __builtin_amdgcn_s_setprio(1);
    #pragma unroll
    for (int s=0;s<16;s++){
      const half8 a = aq[s&3];
      if (s < 12) aq[s&3] = *(const half8*)(ra + (qkB ^ (uint32)((s+4)<<5)));
      S = __builtin_amdgcn_mfma_f32_32x32x16_f16(a, v8[s], S, 0,0,0);
    }
    __builtin_amdgcn_s_setprio(0);

    float p[16];
    #pragma unroll
    for (int r=0;r<16;r++) p[r] = S[r] + m2v[r>>2][r&3];

    // ---- online softmax (pairwise trees) ----
    float t01=fmaxf(p[0],p[1]),   t23=fmaxf(p[2],p[3]),   t45=fmaxf(p[4],p[5]),   t67=fmaxf(p[6],p[7]);
    float t89=fmaxf(p[8],p[9]),   tAB=fmaxf(p[10],p[11]), tCD=fmaxf(p[12],p[13]), tEF=fmaxf(p[14],p[15]);
    float q03=fmaxf(t01,t23), q47=fmaxf(t45,t67), q8B=fmaxf(t89,tAB), qCF=fmaxf(tCD,tEF);
    float tm = fmaxf(fmaxf(q03,q47), fmaxf(q8B,qCF));
    tm = fmaxf(tm, __shfl_xor(tm, 32));
    if (__any(tm > mrun + 8.0f)){
      const float nm = fmaxf(mrun, tm);
      const float sc = __expf(mrun - nm);
      lrun *= sc; mrun = nm;
      #pragma unroll
      for (int b=0;b<8;b++) oacc[b] *= sc;
    }
    #pragma unroll
    for (int r=0;r<16;r++) p[r] = __expf(p[r] - mrun);

    // ---- P -> f16 B-frags in-register ----
    uint32 D[8];
    #pragma unroll
    for (int i=0;i<8;i++){
      union { __fp16 h2 __attribute__((ext_vector_type(2))); uint32 u; } cv;
      cv.h2 = __builtin_amdgcn_cvt_pkrtz(p[2*i], p[2*i+1]);
      D[i] = cv.u;
    }
    uint32 wq[8];
    {
      const uint32 tD0 = (uint32)__shfl_xor((int)D[0], 32);
      const uint32 tD1 = (uint32)__shfl_xor((int)D[1], 32);
      const uint32 tD2 = (uint32)__shfl_xor((int)D[2], 32);
      const uint32 tD3 = (uint32)__shfl_xor((int)D[3], 32);
      const uint32 tD4 = (uint32)__shfl_xor((int)D[4], 32);
      const uint32 tD5 = (uint32)__shfl_xor((int)D[5], 32);
      const uint32 tD6 = (uint32)__shfl_xor((int)D[6], 32);
      const uint32 tD7 = (uint32)__shfl_xor((int)D[7], 32);
      const bool lo = (hi == 0);
      wq[0] = lo ? D[0] : tD2;  wq[1] = lo ? D[1] : tD3;
      wq[2] = lo ? tD0 : D[2];  wq[3] = lo ? tD1 : D[3];
      wq[4] = lo ? D[4] : tD6;  wq[5] = lo ? D[5] : tD7;
      wq[6] = lo ? tD4 : D[6];  wq[7] = lo ? tD5 : D[7];
    }
    union { uint32 u[4]; half8 h; } pb1, pb2;
    pb1.u[0]=wq[0]; pb1.u[1]=wq[1]; pb1.u[2]=wq[2]; pb1.u[3]=wq[3];
    pb2.u[0]=wq[4]; pb2.u[1]=wq[5]; pb2.u[2]=wq[6]; pb2.u[3]=wq[7];

    // ---- PV with explicit 2x2-deep read-ahead ----
    const char* mtb = lds + MT_OFF + bufO;
    const char* a1 = (const char*)(mtb + pvB);
    const char* a2 = (const char*)(mtb + (pvB ^ 32u));
    half8 r1[2], r2[2];
    r1[0] = *(const half8*)(a1);
    r2[0] = *(const half8*)(a2);
    __builtin_amdgcn_s_setprio(1);
    #pragma unroll
    for (int b=0;b<8;b++){
      const half8 A1 = r1[b&1];
      const half8 A2 = r2[b&1];
      if (b < 7){
        r1[(b+1)&1] = *(const half8*)(a1 + (b+1)*2048);
        r2[(b+1)&1] = *(const half8*)(a2 + (b+1)*2048);
      }
      oacc[b] = __builtin_amdgcn_mfma_f32_32x32x16_f16(A1, pb1.h, oacc[b], 0,0,0);
      oacc[b] = __builtin_amdgcn_mfma_f32_32x32x16_f16(A2, pb2.h, oacc[b], 0,0,0);
    }
    __builtin_amdgcn_s_setprio(0);

    // ---- l-sum (pairwise tree) ----
    float s01=p[0]+p[1],   s23=p[2]+p[3],   s45=p[4]+p[5],   s67=p[6]+p[7];
    float s89=p[8]+p[9],   sAB=p[10]+p[11], sCD=p[12]+p[13], sEF=p[14]+p[15];
    float u03=s01+s23, u47=s45+s67, u8B=s89+sAB, uCF=sCD+sEF;
    float ps = (u03+u47) + (u8B+uCF);
    ps += __shfl_xor(ps, 32); lrun += ps;

    m2p += KT;
    __syncthreads();
  }

  {
    __hip_bfloat16* Op = Opart + (size_t)c*N1*BQ + (q0 + row);
    #pragma unroll
    for (int b=0;b<8;b++){
      #pragma unroll
      for (int r=0;r<16;r++){
        const int d = 32*b + (r&3) + 8*(r>>2) + 4*hi;
        Op[(size_t)d*BQ] = __float2bfloat16(oacc[b][r]);
      }
    }
    if (hi == 0){
      mpart[(size_t)c*BQ + q0 + row] = mrun;
      lpart[(size_t)c*BQ + q0 + row] = lrun;
    }
  }
}

// ---- combine: fused wprep+wsum. 512 blocks = 8 q-tiles(64q) x 64 d-tiles(4d). ----
__global__ __launch_bounds__(256) void mhn_combine_k(
    const float* __restrict__ v, const float* __restrict__ mask,
    const __hip_bfloat16* __restrict__ Opart, const float* __restrict__ mpart,
    const float* __restrict__ lpart, float* __restrict__ out, int nchunk)
{
  __shared__ float Wl[128][64];
  __shared__ float red[4][64];
  __shared__ float Mq[64];
  __shared__ float iLq[64];
  __shared__ float T[256];

  const int bid = blockIdx.x;
  const int q0  = (bid & 7) * 64;
  const int d0  = (bid >> 3) * 4;
  const int t   = threadIdx.x;
  const int q   = t & 63;
  const int cg  = t >> 6;
  const int nc4 = nchunk >> 2;

  // phase 1: W[c][q] = exp(m_c - M_q), invL[q]  (per q-tile, redundant per d-tile)
  float mx = -INFINITY;
  for (int k=0;k<nc4;k++)
    mx = fmaxf(mx, mpart[(size_t)(cg*nc4+k)*BQ + q0 + q]);
  red[cg][q] = mx;
  __syncthreads();
  if (t < 64) Mq[t] = fmaxf(fmaxf(red[0][t],red[1][t]), fmaxf(red[2][t],red[3][t]));
  __syncthreads();
  const float M = Mq[q];
  float ls = 0.f;
  for (int k=0;k<nc4;k++){
    const int cc = cg*nc4 + k;
    const float e = __expf(mpart[(size_t)cc*BQ + q0 + q] - M);
    Wl[cc][q] = e;
    ls += lpart[(size_t)cc*BQ + q0 + q] * e;
  }
  red[cg][q] = ls;
  __syncthreads();
  if (t < 64) iLq[t] = 1.0f / (((red[0][t]+red[1][t]) + (red[2][t]+red[3][t])));
  __syncthreads();

  // phase 2: acc over chunks (q-coalesced Opart reads)
  const int dl = t >> 6;
  const __hip_bfloat16* op = Opart + (size_t)(d0+dl)*BQ + q0 + q;
  float acc = 0.f;
  #pragma unroll 8
  for (int c2=0; c2<nchunk; c2++)
    acc += __bfloat162float(op[(size_t)c2*N1*BQ]) * Wl[c2][q];
  T[q*4 + dl] = acc * iLq[q];
  __syncthreads();

  // phase 3: transposed write (16B runs)
  const int q2 = t >> 2, d2 = t & 3;
  const size_t oi = (size_t)(q0+q2)*N1 + d0 + d2;
  const float vv = v[oi], mk = mask[oi];
  out[oi] = vv + 0.5f*(T[t] - vv)*mk;
}

extern "C" void kernel_launch(void* const* d_in, const int* in_sizes, int n_in,
                              void* d_out, int out_size, void* d_ws, size_t ws_size,
                              hipStream_t stream)
{
  (void)in_sizes; (void)n_in; (void)out_size;
  const float* v    = (const float*)d_in[0];
  const float* mask = (const float*)d_in[1];
  const float* Mem  = (const float*)d_in[2];
  float* out = (float*)d_out;

  // ws: MemA f16 | MemT f16 | m2 f32 | Opart bf16 | mpart | lpart
  const size_t fixedB   = (size_t)N2T*N1*2*2 + (size_t)N2T*4;
  const size_t perChunk = (size_t)BQ*N1*2 + (size_t)BQ*8;
  int nchunk = 128;
  while (nchunk > 4 && fixedB + (size_t)nchunk*perChunk > ws_size) nchunk >>= 1;

  char* wsb = (char*)d_ws;
  _Float16* MemA = (_Float16*)wsb;
  _Float16* MemT = (_Float16*)(wsb + (size_t)N2T*N1*2);
  float*    m2g  = (float*)(wsb + (size_t)N2T*N1*4);
  char* pb = wsb + fixedB;
  __hip_bfloat16* Opart = (__hip_bfloat16*)pb;
  float* mpart = (float*)(pb + (size_t)nchunk*BQ*N1*2);
  float* lpart = mpart + (size_t)nchunk*BQ;

  const int CK = N2T / nchunk;
  const int nt = CK / KT;

  mhn_prep_k<<<dim3(N2T/KT), dim3(256), 0, stream>>>(Mem, MemA, MemT, m2g);
  mhn_flash_k<<<dim3(4*nchunk), dim3(256), 0, stream>>>(MemA, MemT, m2g, v, Opart, mpart, lpart, CK, nt);
  mhn_combine_k<<<dim3(512), dim3(256), 0, stream>>>(v, mask, Opart, mpart, lpart, out, nchunk);
}